// Round 18
// baseline (358.081 us; speedup 1.0000x reference)
//
#include <hip/hip_runtime.h>

#define D 64
#define NGRAPH 128
#define NCLS 10
#define BN_EPS 1e-5f
#define BUCK_SZ 512   // dsts per bucket (2^9)
#define EPB 8192      // edges per block in pass 1

typedef __attribute__((ext_vector_type(8))) __bf16 bf16x8;
typedef __attribute__((ext_vector_type(4))) float floatx4;

union BF8 { bf16x8 v; ushort u[8]; };

// fp32 -> bf16 round-to-nearest-even (bits).
__device__ __forceinline__ unsigned f2bf_rne(float f) {
  unsigned u = __float_as_uint(f);
  return (u + 0x7FFFu + ((u >> 16) & 1u)) >> 16;
}
__device__ __forceinline__ unsigned pack2bf(float a, float b) {
  return f2bf_rne(a) | (f2bf_rne(b) << 16);
}
// Unpack 4 packed bf16 (uint2) -> float4.
__device__ __forceinline__ float4 bf4_to_f4(uint2 u) {
  float4 r;
  r.x = __uint_as_float(u.x << 16);
  r.y = __uint_as_float(u.x & 0xFFFF0000u);
  r.z = __uint_as_float(u.y << 16);
  r.w = __uint_as_float(u.y & 0xFFFF0000u);
  return r;
}

// BN scale/shift for feature f from raw stats (sum, sumsq); invN host-side.
__device__ __forceinline__ void bn_sc_sh(
    const float* __restrict__ stats, const float* __restrict__ gamma,
    const float* __restrict__ beta, float invN, int f, float* sc, float* sh) {
  float mean = stats[f] * invN;
  float var = stats[D + f] * invN - mean * mean;
  float s = gamma[f] * rsqrtf(var + BN_EPS);
  *sc = s;
  *sh = beta[f] - mean * s;
}

// Split 8 fp32 into bf16 hi (truncation) + bf16 lo (residual, truncated).
__device__ __forceinline__ void split8(float4 a, float4 b,
                                       bf16x8* hi, bf16x8* lo) {
  float f[8] = {a.x, a.y, a.z, a.w, b.x, b.y, b.z, b.w};
  BF8 H, L;
#pragma unroll
  for (int t = 0; t < 8; t++) {
    unsigned u = __float_as_uint(f[t]);
    H.u[t] = (ushort)(u >> 16);
    float hf = __uint_as_float(u & 0xFFFF0000u);
    float lf = f[t] - hf;
    L.u[t] = (ushort)(__float_as_uint(lf) >> 16);
  }
  *hi = H.v;
  *lo = L.v;
}

// ===========================================================================
// CSR build pass 1: block-aggregated bucket sort of edges.
// ===========================================================================
__global__ __launch_bounds__(256) void bucket_scatter_kernel(
    const int* __restrict__ ei, int* __restrict__ gcnt, int* __restrict__ pk,
    int E, int capB, int nbuck) {
  __shared__ int hist[256];
  __shared__ int base[256];
  int t = threadIdx.x;
  int e0 = blockIdx.x * EPB;
  int e1 = min(e0 + EPB, E);
  hist[t] = 0;
  __syncthreads();
  for (int e = e0 + t; e < e1; e += 256)
    atomicAdd(&hist[ei[E + e] >> 9], 1);
  __syncthreads();
  int h = hist[t];
  if (t < nbuck && h > 0) base[t] = atomicAdd(&gcnt[t], h);
  hist[t] = 0;  // reuse as per-bucket cursor
  __syncthreads();
  for (int e = e0 + t; e < e1; e += 256) {
    int s = ei[e];
    int d = ei[E + e];
    int b = d >> 9;
    int pos = base[b] + atomicAdd(&hist[b], 1);
    if (pos < capB) pk[(size_t)b * capB + pos] = (s << 9) | (d & (BUCK_SZ - 1));
  }
}

// Exclusive scan of per-bucket totals (nbuck <= 256); row_start[N] = total.
__global__ void bucket_scan_kernel(const int* __restrict__ gcnt,
                                   int* __restrict__ bstart,
                                   int* __restrict__ row_start,
                                   int nbuck, int N, int capB) {
  __shared__ int s[256];
  int t = threadIdx.x;
  int v = (t < nbuck) ? min(gcnt[t], capB) : 0;
  s[t] = v;
  __syncthreads();
  for (int off = 1; off < 256; off <<= 1) {
    int add = (t >= off) ? s[t - off] : 0;
    __syncthreads();
    s[t] += add;
    __syncthreads();
  }
  if (t < nbuck) bstart[t] = s[t] - v;
  if (t == 0) {
    bstart[nbuck] = s[255];
    row_start[N] = s[255];
  }
}

// Pass 2: one block per bucket: LDS histogram, scan, place.
__global__ __launch_bounds__(256) void bucket_place_kernel(
    const int* __restrict__ pk, const int* __restrict__ gcnt,
    const int* __restrict__ bstart, int* __restrict__ row_start,
    int* __restrict__ csr_src, int N, int capB) {
  __shared__ int hist[BUCK_SZ];
  __shared__ int scn[256];
  __shared__ int cur[BUCK_SZ];
  int b = blockIdx.x;
  int t = threadIdx.x;
  hist[t] = 0;
  hist[t + 256] = 0;
  int cnt = min(gcnt[b], capB);
  const int* seg = pk + (size_t)b * capB;
  __syncthreads();
  for (int e = t; e < cnt; e += 256)
    atomicAdd(&hist[seg[e] & (BUCK_SZ - 1)], 1);
  __syncthreads();
  scn[t] = hist[2 * t] + hist[2 * t + 1];
  __syncthreads();
  for (int off = 1; off < 256; off <<= 1) {
    int add = (t >= off) ? scn[t - off] : 0;
    __syncthreads();
    scn[t] += add;
    __syncthreads();
  }
  int base = bstart[b];
  int ex = (t == 0) ? 0 : scn[t - 1];
  int c0 = base + ex;
  int c1 = c0 + hist[2 * t];
  cur[2 * t] = c0;
  cur[2 * t + 1] = c1;
  int dst0 = b * BUCK_SZ + 2 * t;
  if (dst0 < N) row_start[dst0] = c0;
  if (dst0 + 1 < N) row_start[dst0 + 1] = c1;
  __syncthreads();
  for (int e = t; e < cnt; e += 256) {
    int p = seg[e];
    int slot = atomicAdd(&cur[p & (BUCK_SZ - 1)], 1);
    csr_src[slot] = p >> 9;
  }
}

// ===========================================================================
// Weight split+swizzle prep (once).
// ===========================================================================
__global__ __launch_bounds__(256) void wsplit_kernel(
    const float* __restrict__ Wrel, const float* __restrict__ Wroot,
    ushort* __restrict__ wfrag) {
  int l = blockIdx.x;  // 0..2
  const float* Wr = Wrel + l * 4096;
  const float* Wo = Wroot + l * 4096;
  ushort* base = wfrag + l * 16384;
  for (int slot = threadIdx.x; slot < 1024; slot += 256) {
    int kt = slot >> 8, nt = (slot >> 6) & 3, lane = slot & 63;
    int quad = lane >> 4, c = lane & 15;
    ushort* ph = base + (((kt * 4 + nt) * 2 + 0) * 64 + lane) * 8;
    ushort* pl = base + (((kt * 4 + nt) * 2 + 1) * 64 + lane) * 8;
#pragma unroll
    for (int j = 0; j < 8; j++) {
      int k = kt * 32 + quad * 8 + j;
      int n = nt * 16 + c;
      float w = (k < 64) ? Wr[k * 64 + n] : Wo[(k - 64) * 64 + n];
      unsigned u = __float_as_uint(w);
      ph[j] = (ushort)(u >> 16);
      float lf = w - __uint_as_float(u & 0xFFFF0000u);
      pl[j] = (ushort)(__float_as_uint(lf) >> 16);
    }
  }
}

// ===========================================================================
// x -> packed bf16 (RNE), once per call. 8 elements/thread. Elements with
// base >= n (the zero pad row N) are written as zeros.
// ===========================================================================
__global__ __launch_bounds__(256) void xprep_kernel(
    const float* __restrict__ x, ushort* __restrict__ xbf, int n, int ntot) {
  int base = (blockIdx.x * 256 + threadIdx.x) * 8;
  if (base >= ntot) return;
  uint4 o = {0, 0, 0, 0};
  if (base < n) {
    float4 a = *(const float4*)(x + base);
    float4 b = *(const float4*)(x + base + 4);
    o.x = pack2bf(a.x, a.y);
    o.y = pack2bf(a.z, a.w);
    o.z = pack2bf(b.x, b.y);
    o.w = pack2bf(b.z, b.w);
  }
  *(uint4*)(xbf + base) = o;
}

// ===========================================================================
// Per-node normalize: xnorm = bf16(relu(hraw*sc + sh)), sc/sh inline from
// raw stats. Replaces per-edge BN in gather (deg~12.5x less work) and
// per-tile BN in mm. Pad row N written as zeros (enables mask-free gather).
// ===========================================================================
__global__ __launch_bounds__(256) void norm_kernel(
    const ushort* __restrict__ hraw, const float* __restrict__ stats,
    const float* __restrict__ gamma, const float* __restrict__ beta,
    float invN, ushort* __restrict__ xnorm, int n, int ntot) {
  int base = (blockIdx.x * 256 + threadIdx.x) * 8;
  if (base >= ntot) return;
  uint4 o = {0, 0, 0, 0};
  if (base < n) {
    int f0 = base & 63;
    uint4 u = *(const uint4*)(hraw + base);
    uint2 ulo = {u.x, u.y}, uhi = {u.z, u.w};
    float4 a = bf4_to_f4(ulo);
    float4 b = bf4_to_f4(uhi);
    float sc[8], sh[8];
#pragma unroll
    for (int k = 0; k < 8; k++)
      bn_sc_sh(stats, gamma, beta, invN, f0 + k, &sc[k], &sh[k]);
    a.x = fmaxf(a.x * sc[0] + sh[0], 0.f);
    a.y = fmaxf(a.y * sc[1] + sh[1], 0.f);
    a.z = fmaxf(a.z * sc[2] + sh[2], 0.f);
    a.w = fmaxf(a.w * sc[3] + sh[3], 0.f);
    b.x = fmaxf(b.x * sc[4] + sh[4], 0.f);
    b.y = fmaxf(b.y * sc[5] + sh[5], 0.f);
    b.z = fmaxf(b.z * sc[6] + sh[6], 0.f);
    b.w = fmaxf(b.w * sc[7] + sh[7], 0.f);
    o.x = pack2bf(a.x, a.y);
    o.y = pack2bf(a.z, a.w);
    o.z = pack2bf(b.x, b.y);
    o.w = pack2bf(b.z, b.w);
  }
  *(uint4*)(xnorm + base) = o;
}

// ===========================================================================
// Gather v6: pure sum, NO normalize, NO masks. One wave per dst row, block =
// 4 rows. Row indices preloaded in one coalesced load; value addresses via
// __shfl; out-of-range edge slots clamp to the ZERO PAD ROW (index N) so
// their loads contribute 0 — no mask arithmetic at all. Inner loop: shfl,
// load, unpack, add. Cross-quad shfl reduce; quad 0 writes fp32 msg row.
// ===========================================================================
__global__ __launch_bounds__(256) void gather_kernel(
    const ushort* __restrict__ xbf, const int* __restrict__ csr_src,
    const int* __restrict__ row_start, float* __restrict__ msg, int N) {
  int i = blockIdx.x * 4 + (threadIdx.x >> 6);
  int lane = threadIdx.x & 63;
  int q = lane >> 4;         // edge sub-slot 0..3
  int f = (lane & 15) << 2;  // feature quad base
  if (i >= N) return;
  int e0 = row_start[i], e1 = row_start[i + 1];
  int cnt = e1 - e0;
  int myidx = csr_src[e0 + lane];  // coalesced; overread lands in pk (ours)
  float4 acc = {0.f, 0.f, 0.f, 0.f};

  int cnt64 = min(cnt, 64);
  for (int base = 0; base < cnt64; base += 16) {
    int j0 = base + q;  // this quad's 4 edges: j0, j0+4, j0+8, j0+12
    int s0 = __shfl(myidx, j0);
    int s1 = __shfl(myidx, j0 + 4);
    int s2 = __shfl(myidx, j0 + 8);
    int s3 = __shfl(myidx, j0 + 12);
    s0 = (j0 < cnt) ? s0 : N;        // zero pad row: adds 0, no mask needed
    s1 = (j0 + 4 < cnt) ? s1 : N;
    s2 = (j0 + 8 < cnt) ? s2 : N;
    s3 = (j0 + 12 < cnt) ? s3 : N;
    float4 v0 = bf4_to_f4(*(const uint2*)(xbf + (size_t)s0 * D + f));
    float4 v1 = bf4_to_f4(*(const uint2*)(xbf + (size_t)s1 * D + f));
    float4 v2 = bf4_to_f4(*(const uint2*)(xbf + (size_t)s2 * D + f));
    float4 v3 = bf4_to_f4(*(const uint2*)(xbf + (size_t)s3 * D + f));
    acc.x += (v0.x + v1.x) + (v2.x + v3.x);
    acc.y += (v0.y + v1.y) + (v2.y + v3.y);
    acc.z += (v0.z + v1.z) + (v2.z + v3.z);
    acc.w += (v0.w + v1.w) + (v2.w + v3.w);
  }

  // Rare tail: rows with degree > 64.
  for (int e = e0 + 64 + q; e < e1; e += 4) {
    float4 v = bf4_to_f4(*(const uint2*)(xbf + (size_t)csr_src[e] * D + f));
    acc.x += v.x; acc.y += v.y; acc.z += v.z; acc.w += v.w;
  }

  acc.x += __shfl_xor(acc.x, 16); acc.x += __shfl_xor(acc.x, 32);
  acc.y += __shfl_xor(acc.y, 16); acc.y += __shfl_xor(acc.y, 32);
  acc.z += __shfl_xor(acc.z, 16); acc.z += __shfl_xor(acc.z, 32);
  acc.w += __shfl_xor(acc.w, 16); acc.w += __shfl_xor(acc.w, 32);
  if (q == 0) *(float4*)(msg + (size_t)i * D + f) = acc;
}

// ===========================================================================
// mm via MFMA split-bf16. Root-term input: fp32 x (use_bf=0, layer 0) or
// pre-normalized bf16 xnorm (use_bf=1, layers 1,2) — NO inline BN anymore.
// Outputs: raw-h bf16 (wbf=1, layers 0,1) and/or fp32 h (wh=1, layer 2).
// BN stats of h accumulated into stats_cur (pre-zeroed).
// ===========================================================================
__global__ __launch_bounds__(256, 1) void mm_mfma_kernel(
    const float* __restrict__ msg, const float* __restrict__ xf32,
    const ushort* __restrict__ xbfin,
    const ushort* __restrict__ wfrag, const float* __restrict__ brel,
    int use_bf, float* __restrict__ h, ushort* __restrict__ hbf,
    int wh, int wbf, float* __restrict__ stats_cur,
    int N, int ntiles, int nwaves) {
  __shared__ float ssum[4][64];
  __shared__ float ssq[4][64];
  int tid = threadIdx.x;
  int lane = tid & 63;
  int wvid = tid >> 6;
  int wv = (blockIdx.x * 256 + tid) >> 6;
  int quad = lane >> 4;
  int lo4 = lane & 15;

  bf16x8 bf[4][4][2];
#pragma unroll
  for (int kt = 0; kt < 4; kt++)
#pragma unroll
    for (int nt = 0; nt < 4; nt++)
#pragma unroll
      for (int s = 0; s < 2; s++)
        bf[kt][nt][s] =
            *(const bf16x8*)(wfrag + (((kt * 4 + nt) * 2 + s) * 64 + lane) * 8);

  float bias[4];
#pragma unroll
  for (int nt = 0; nt < 4; nt++) bias[nt] = brel[nt * 16 + lo4];

  float psum[4] = {0.f, 0.f, 0.f, 0.f};
  float psq[4] = {0.f, 0.f, 0.f, 0.f};

  for (int t = wv; t < ntiles; t += nwaves) {
    int i0 = t * 16;
    int row = i0 + lo4;
    if (row >= N) row = N - 1;
    bf16x8 ahi[4], alo[4];
#pragma unroll
    for (int kt = 0; kt < 4; kt++) {
      float4 a, b;
      if (kt < 2) {
        const float* p = msg + (size_t)row * D + (kt & 1) * 32 + quad * 8;
        a = *(const float4*)p;
        b = *(const float4*)(p + 4);
      } else if (use_bf) {
        const ushort* p = xbfin + (size_t)row * D + (kt & 1) * 32 + quad * 8;
        uint4 u = *(const uint4*)p;
        uint2 ulo = {u.x, u.y}, uhi = {u.z, u.w};
        a = bf4_to_f4(ulo);
        b = bf4_to_f4(uhi);
      } else {
        const float* p = xf32 + (size_t)row * D + (kt & 1) * 32 + quad * 8;
        a = *(const float4*)p;
        b = *(const float4*)(p + 4);
      }
      split8(a, b, &ahi[kt], &alo[kt]);
    }
#pragma unroll
    for (int nt = 0; nt < 4; nt++) {
      floatx4 acc = {bias[nt], bias[nt], bias[nt], bias[nt]};
#pragma unroll
      for (int kt = 0; kt < 4; kt++) {
        acc = __builtin_amdgcn_mfma_f32_16x16x32_bf16(ahi[kt], bf[kt][nt][0],
                                                      acc, 0, 0, 0);
        acc = __builtin_amdgcn_mfma_f32_16x16x32_bf16(ahi[kt], bf[kt][nt][1],
                                                      acc, 0, 0, 0);
        acc = __builtin_amdgcn_mfma_f32_16x16x32_bf16(alo[kt], bf[kt][nt][0],
                                                      acc, 0, 0, 0);
      }
#pragma unroll
      for (int r = 0; r < 4; r++) {
        int grow = i0 + quad * 4 + r;
        if (grow < N) {
          float v = acc[r];
          size_t idx = (size_t)grow * D + nt * 16 + lo4;
          if (wh) h[idx] = v;
          if (wbf) hbf[idx] = (ushort)f2bf_rne(v);
          psum[nt] += v;
          psq[nt] += v * v;
        }
      }
    }
  }

#pragma unroll
  for (int nt = 0; nt < 4; nt++) {
    float s = psum[nt], q = psq[nt];
    s += __shfl_xor(s, 16); s += __shfl_xor(s, 32);
    q += __shfl_xor(q, 16); q += __shfl_xor(q, 32);
    if (lane < 16) { ssum[wvid][nt * 16 + lane] = s; ssq[wvid][nt * 16 + lane] = q; }
  }
  __syncthreads();
  if (tid < 64) {
    atomicAdd(&stats_cur[tid],
              ssum[0][tid] + ssum[1][tid] + ssum[2][tid] + ssum[3][tid]);
  } else if (tid < 128) {
    int c = tid - 64;
    atomicAdd(&stats_cur[D + c],
              ssq[0][c] + ssq[1][c] + ssq[2][c] + ssq[3][c]);
  }
}

// ---------------------------------------------------------------------------
// Final layer: inline BN + ReLU fused with graph mean-pool (batch sorted).
__global__ __launch_bounds__(256) void norm_relu_pool_kernel(
    const float* __restrict__ h, const float* __restrict__ stats,
    const float* __restrict__ gamma, const float* __restrict__ beta,
    float invN, const int* __restrict__ batch, float* __restrict__ pooled,
    int N) {
  int j = threadIdx.x & 63;
  int q = threadIdx.x >> 6;
  int i0 = blockIdx.x * 256;
  float sc, sh;
  bn_sc_sh(stats, gamma, beta, invN, j, &sc, &sh);
  int curg = -1;
  float acc = 0.f;
  for (int r = q; r < 256; r += 4) {
    int i = i0 + r;
    if (i >= N) break;
    int b = batch[i];
    float v = fmaxf(h[(size_t)i * D + j] * sc + sh, 0.f);
    if (b != curg) {
      if (curg >= 0) atomicAdd(&pooled[curg * D + j], acc);
      curg = b;
      acc = v;
    } else {
      acc += v;
    }
  }
  if (curg >= 0) atomicAdd(&pooled[curg * D + j], acc);
}

// ---------------------------------------------------------------------------
// Classifier with fused per-graph counts (binary search on sorted batch).
__global__ void cls_kernel(const float* __restrict__ pooled,
                           const int* __restrict__ batch,
                           const float* __restrict__ Wcls,
                           const float* __restrict__ bcls,
                           float* __restrict__ out, int N) {
  int tid = blockIdx.x * blockDim.x + threadIdx.x;
  if (tid >= NGRAPH * NCLS) return;
  int g = tid / NCLS, c = tid % NCLS;
  int lo = 0, hi = N;
  while (lo < hi) { int m = (lo + hi) >> 1; if (batch[m] < g) lo = m + 1; else hi = m; }
  int start = lo;
  lo = 0; hi = N;
  while (lo < hi) { int m = (lo + hi) >> 1; if (batch[m] <= g) lo = m + 1; else hi = m; }
  float inv = 1.f / fmaxf((float)(lo - start), 1.f);
  float acc = bcls[c];
#pragma unroll 8
  for (int k = 0; k < D; k++) acc += pooled[g * D + k] * inv * Wcls[k * NCLS + c];
  out[g * NCLS + c] = acc;
}

// ---------------------------------------------------------------------------
extern "C" void kernel_launch(void* const* d_in, const int* in_sizes, int n_in,
                              void* d_out, int out_size, void* d_ws, size_t ws_size,
                              hipStream_t stream) {
  const float* x      = (const float*)d_in[0];
  const int*   ei     = (const int*)d_in[1];
  const int*   batch  = (const int*)d_in[2];
  const float* W_rel  = (const float*)d_in[3];
  const float* b_rel  = (const float*)d_in[4];
  const float* W_root = (const float*)d_in[5];
  const float* gamma  = (const float*)d_in[6];
  const float* beta   = (const float*)d_in[7];
  const float* W_cls  = (const float*)d_in[8];
  const float* b_cls  = (const float*)d_in[9];
  float* out = (float*)d_out;

  int E = in_sizes[1] / 2;
  int N = in_sizes[2];
  size_t nd = (size_t)N * D;
  size_t ndp = (size_t)(N + 1) * D;  // +1 zero pad row for mask-free gather
  int nbuck = (N + BUCK_SZ - 1) / BUCK_SZ;  // 196 for N=100k (<=256)
  int capB = ((2 * E / nbuck) + 511) & ~511;
  if (capB < 1024) capB = 1024;
  float invN = 1.0f / (float)N;

  // Workspace layout.
  float* bufA    = (float*)d_ws;                 // N*D: fp32 h (layer 2 only)
  float* bufB    = bufA + nd;                    // N*D: msg
  ushort* xnorm  = (ushort*)(bufB + nd);         // (N+1)*D bf16 normalized in
  ushort* hraw   = xnorm + ndp;                  // N*D bf16 raw h out
  float* stats3  = (float*)(hraw + nd);          // 3 * 2*D  -- zeroed
  float* pooled  = stats3 + 3 * 2 * D;           // NGRAPH*D -- zeroed
  int* gcnt      = (int*)(pooled + NGRAPH * D);  // nbuck -- zeroed
  ushort* wfrag  = (ushort*)(gcnt + ((nbuck + 3) & ~3));  // 3*16384 ushorts
  int* bstart    = (int*)(wfrag + 3 * 16384);    // nbuck+1
  int* row_start = bstart + nbuck + 1;           // N+1
  int* csr_src   = row_start + N + 1;            // E
  int* pk        = csr_src + E;                  // nbuck*capB

  size_t zero_bytes = (size_t)(3 * 2 * D + NGRAPH * D) * 4 +
                      (size_t)nbuck * 4;
  hipMemsetAsync(stats3, 0, zero_bytes, stream);

  // ---- CSR build + weight/x prep (once) ----
  bucket_scatter_kernel<<<(E + EPB - 1) / EPB, 256, 0, stream>>>(
      ei, gcnt, pk, E, capB, nbuck);
  bucket_scan_kernel<<<1, 256, 0, stream>>>(gcnt, bstart, row_start, nbuck, N, capB);
  bucket_place_kernel<<<nbuck, 256, 0, stream>>>(pk, gcnt, bstart, row_start,
                                                 csr_src, N, capB);
  wsplit_kernel<<<3, 256, 0, stream>>>(W_rel, W_root, wfrag);
  xprep_kernel<<<(int)((ndp / 8 + 255) / 256), 256, 0, stream>>>(
      x, xnorm, (int)nd, (int)ndp);

  // ---- Layers ----
  const int MM_BLOCKS = 512;
  const int MM_WAVES = MM_BLOCKS * 4;
  int ntiles = (N + 15) / 16;
  int nblk_norm = (int)((ndp / 8 + 255) / 256);
  for (int l = 0; l < 3; l++) {
    int use_bf = (l > 0) ? 1 : 0;
    int wbf = (l < 2) ? 1 : 0;
    int wh = (l == 2) ? 1 : 0;
    float* st_cur = stats3 + l * 2 * D;

    gather_kernel<<<(N + 3) / 4, 256, 0, stream>>>(xnorm, csr_src, row_start,
                                                   bufB, N);

    mm_mfma_kernel<<<MM_BLOCKS, 256, 0, stream>>>(
        bufB, x, xnorm, wfrag + l * 16384, b_rel + l * D,
        use_bf, bufA, hraw, wh, wbf, st_cur,
        N, ntiles, MM_WAVES);

    if (l < 2) {
      // Per-node normalize for the next layer's input (overwrites xnorm).
      norm_kernel<<<nblk_norm, 256, 0, stream>>>(
          hraw, st_cur, gamma + l * D, beta + l * D, invN, xnorm,
          (int)nd, (int)ndp);
    }
  }

  norm_relu_pool_kernel<<<(N + 255) / 256, 256, 0, stream>>>(
      bufA, stats3 + 2 * 2 * D, gamma + 2 * D, beta + 2 * D, invN, batch,
      pooled, N);
  cls_kernel<<<(NGRAPH * NCLS + 255) / 256, 256, 0, stream>>>(
      pooled, batch, W_cls, b_cls, out, N);
}